// Round 13
// baseline (1953.092 us; speedup 1.0000x reference)
//
#include <hip/hip_runtime.h>
#include <hip/hip_fp16.h>

typedef _Float16 half8 __attribute__((ext_vector_type(8)));
typedef float floatx4 __attribute__((ext_vector_type(4)));
typedef unsigned int uintx4 __attribute__((ext_vector_type(4)));

#define INPUT  512
#define HIDDEN 1024
#define OUTPUT 256
#define BATCH  128
#define SEQ    512

// ---------------------------------------------------------------------------
// K0: transpose + fp32->fp16:  W_h [K][N] f32 -> WhT [N][K] f16
// ---------------------------------------------------------------------------
__global__ __launch_bounds__(256) void transpose_f32_to_f16(
    const float* __restrict__ in, _Float16* __restrict__ out, int K, int N) {
  __shared__ float tile[32][33];
  int bi = blockIdx.x;
  int bj = blockIdx.y;
  int cc = threadIdx.x & 31;
  int rr = threadIdx.x >> 5;
#pragma unroll
  for (int s = 0; s < 4; ++s) {
    int r = rr + 8 * s;
    tile[r][cc] = in[(size_t)(bi * 32 + r) * N + bj * 32 + cc];
  }
  __syncthreads();
#pragma unroll
  for (int s = 0; s < 4; ++s) {
    int nl = rr + 8 * s;
    out[(size_t)(bj * 32 + nl) * K + bi * 32 + cc] = (_Float16)tile[cc][nl];
  }
}

// ---------------------------------------------------------------------------
// K0b: pack W_in [512][1024] f32 into MFMA B-fragment order (fp16).
// ---------------------------------------------------------------------------
__global__ __launch_bounds__(256) void pack_win(
    const float* __restrict__ W, _Float16* __restrict__ P) {
  int idx = blockIdx.x * 256 + threadIdx.x;   // 0..524287
  int k = idx >> 10, n = idx & 1023;
  P[((size_t)(k >> 5) << 15) + (n << 5) + (k & 31)] = (_Float16)W[idx];
}

// ---------------------------------------------------------------------------
// K1: xin[S][B][H] = x @ W_in  (time-major). 64x128 tile, 4 waves,
// 8 ntiles/wave, packed-fragment B loads.  (validated, R6/R7)
// ---------------------------------------------------------------------------
__global__ __launch_bounds__(256) void xin_gemm(
    const float* __restrict__ x, const _Float16* __restrict__ WinP,
    _Float16* __restrict__ xin) {
  int bid = blockIdx.x;                     // 8192 blocks
  int bm = (bid & 7) * 128 + ((bid >> 3) & 127);   // 0..1023
  int bn = bid >> 10;                       // 0..7
  int tid = threadIdx.x;
  int l = tid & 63;
  int w = tid >> 6;
  int l15 = l & 15;
  int lk = (l >> 4) << 3;

  int rowbase = bm * 64 + w * 16;
  int colbase = bn * 128;

  floatx4 acc[8];
#pragma unroll
  for (int nt = 0; nt < 8; ++nt) acc[nt] = (floatx4){0.f, 0.f, 0.f, 0.f};

  const float* xrow = x + (size_t)(rowbase + l15) * INPUT;

  for (int k0 = 0; k0 < INPUT; k0 += 32) {
    int ak = k0 + lk;
    float4 xa = *reinterpret_cast<const float4*>(xrow + ak);
    float4 xb = *reinterpret_cast<const float4*>(xrow + ak + 4);
    half8 a;
    a[0] = (_Float16)xa.x; a[1] = (_Float16)xa.y;
    a[2] = (_Float16)xa.z; a[3] = (_Float16)xa.w;
    a[4] = (_Float16)xb.x; a[5] = (_Float16)xb.y;
    a[6] = (_Float16)xb.z; a[7] = (_Float16)xb.w;
    const _Float16* pq = WinP + ((size_t)(k0 >> 5) << 15) + l15 * 32 + lk;
#pragma unroll
    for (int nt = 0; nt < 8; ++nt) {
      half8 b = *reinterpret_cast<const half8*>(pq + (colbase + nt * 16) * 32);
      acc[nt] = __builtin_amdgcn_mfma_f32_16x16x32_f16(a, b, acc[nt], 0, 0, 0);
    }
  }

  int orow = rowbase + ((l >> 4) << 2);
#pragma unroll
  for (int nt = 0; nt < 8; ++nt)
#pragma unroll
    for (int i = 0; i < 4; ++i) {
      int r = orow + i;
      int b = r >> 9;
      int s = r & 511;
      xin[((size_t)s * BATCH + b) * HIDDEN + colbase + nt * 16 + l15] =
          (_Float16)acc[nt][i];
    }
}

// ---------------------------------------------------------------------------
// K2: persistent recurrence — R10 core (proven 977us) + two local deltas:
//   (a) SELECTIVE RETRY: first poll round reads all 8 slabs; retry rounds
//       re-issue only the stale ones (wave-uniform guards, per-slab __any).
//   (b) PAIRED EPILOGUE (numerically proven in R12): thread -> (row er,
//       cols c2,c2+1); one u64 tagged store (contiguous per wave), u32 xin
//       loads, float2 hfinal.  hbuf layout / poll / staging / MFMA / part[]
//       are R10 VERBATIM.
// 128 blocks = 8 batch-groups (16 rows, -> XCD m) x 16 N-slices (64 cols).
// 8 waves = 2 ntile-pairs (g) x 4 K-quarters (kg); W_h stationary in VGPRs.
// ---------------------------------------------------------------------------
__global__ __launch_bounds__(512) void liquid_scan(
    const _Float16* __restrict__ xin,   // [S][B][H]
    const _Float16* __restrict__ WhT,   // [H n][H k]
    const float* __restrict__ b_in, const float* __restrict__ b_h,
    const float* __restrict__ tau,
    unsigned int* hbuf,                 // [2][8][16][1024] tagged u32
    float* __restrict__ hfinal) {       // [B][H] f32
  int blk = blockIdx.x;
  int m = blk & 7;                  // batch group -> XCD m (perf heuristic)
  int j = blk >> 3;                 // N slice, 0..15
  int tid = threadIdx.x;
  int l = tid & 63;
  int w = tid >> 6;                 // 0..7
  int g = w & 1;                    // ntile-pair (32 cols)
  int kg = w >> 1;                  // K quarter (256 k)
  int l15 = l & 15;
  int lk = (l >> 4) << 3;

  __shared__ _Float16 Ald[16][1032];         // h_t tile (R7/R10 proven)
  __shared__ float part[2][2][4][64][4];     // [g][nt2][i][lane][kg-slot]

  // ---- stationary W_h: two ntiles x K-quarter per wave (64 VGPR) ----
  half8 wf0[8], wf1[8];
  {
    const _Float16* wb0 =
        WhT + (size_t)(j * 64 + g * 32 + l15) * HIDDEN + kg * 256 + lk;
    const _Float16* wb1 = wb0 + 16 * HIDDEN;
#pragma unroll
    for (int kt = 0; kt < 8; ++kt) {
      wf0[kt] = *reinterpret_cast<const half8*>(wb0 + kt * 32);
      wf1[kt] = *reinterpret_cast<const half8*>(wb1 + kt * 32);
    }
  }

  // ---- paired epilogue mapping: thread -> (row er, cols c2, c2+1) ----
  const int er = tid >> 5;               // 0..15
  const int c2 = (tid & 31) * 2;         // 0..62 even (local col)
  const int n0 = j * 64 + c2;            // global col
  const int gb = m * 16 + er;            // global batch row
  const float bias0 = b_in[n0] + b_h[n0];
  const float bias1 = b_in[n0 + 1] + b_h[n0 + 1];
  const float it0 = 1.0f / tau[n0];
  const float it1 = 1.0f / tau[n0 + 1];
  float h0 = 0.f, h1 = 0.f;
  const int pg = c2 >> 5;                // part: ntile-pair
  const int pnt = (c2 >> 4) & 1;         // part: ntile within pair
  const int pi = er & 3;                 // part: acc element
  const int plane = ((er >> 2) << 4) | (c2 & 15);   // C/D lane of col c2

  // ---- poll assignment (R10 verbatim): thread's 8 slabs ----
  const int srow = tid >> 8;
  const int scol4 = (tid & 255) * 4;
  unsigned int* gbase = hbuf + m * 16384 + tid * 4;

  // ---- xin 2-deep u32 pipeline (cols n0, n0+1 at row gb) ----
  const unsigned* xu = reinterpret_cast<const unsigned*>(xin);
  const size_t xoff = (size_t)gb * 512 + (n0 >> 1);
  unsigned xc = xu[(size_t)0 * 65536 + xoff];
  unsigned x1v = xu[(size_t)1 * 65536 + xoff];

  for (int t = 0; t < SEQ; ++t) {
    if (t > 0) {
      unsigned int* bp = gbase + (size_t)(t & 1) * 131072;
      const unsigned want = (unsigned)t;
      uintx4 q0, q1, q2, q3, q4, q5, q6, q7;
      // first round: all 8 slabs, fused issue+wait (R5 lesson)
      asm volatile(
          "global_load_dwordx4 %0, %8, off sc1\n\t"
          "global_load_dwordx4 %1, %9, off sc1\n\t"
          "global_load_dwordx4 %2, %10, off sc1\n\t"
          "global_load_dwordx4 %3, %11, off sc1\n\t"
          "global_load_dwordx4 %4, %12, off sc1\n\t"
          "global_load_dwordx4 %5, %13, off sc1\n\t"
          "global_load_dwordx4 %6, %14, off sc1\n\t"
          "global_load_dwordx4 %7, %15, off sc1\n\t"
          "s_waitcnt vmcnt(0)"
          : "=&v"(q0), "=&v"(q1), "=&v"(q2), "=&v"(q3),
            "=&v"(q4), "=&v"(q5), "=&v"(q6), "=&v"(q7)
          : "v"(bp), "v"(bp + 2048), "v"(bp + 4096), "v"(bp + 6144),
            "v"(bp + 8192), "v"(bp + 10240), "v"(bp + 12288),
            "v"(bp + 14336)
          : "memory");
      unsigned need = 0u;
#define CHK(Q, I)                                                         \
      {                                                                   \
        unsigned bad = ((Q[0] ^ want) | (Q[1] ^ want) | (Q[2] ^ want) |   \
                        (Q[3] ^ want)) & 0xFFFFu;                         \
        if (__any(bad != 0u)) need |= (1u << I);                          \
      }
      CHK(q0, 0) CHK(q1, 1) CHK(q2, 2) CHK(q3, 3)
      CHK(q4, 4) CHK(q5, 5) CHK(q6, 6) CHK(q7, 7)
#undef CHK
      // selective retry: only stale slabs (wave-uniform guards)
      while (need) {
#define RETRY(Q, I, WOFF)                                                 \
        if (need & (1u << I)) {                                           \
          asm volatile("global_load_dwordx4 %0, %1, off sc1\n\t"          \
                       "s_waitcnt vmcnt(0)"                               \
                       : "=&v"(Q) : "v"(bp + WOFF) : "memory");           \
          unsigned bad = ((Q[0] ^ want) | (Q[1] ^ want) | (Q[2] ^ want) | \
                          (Q[3] ^ want)) & 0xFFFFu;                       \
          if (!__any(bad != 0u)) need &= ~(1u << I);                      \
        }
        RETRY(q0, 0, 0) RETRY(q1, 1, 2048) RETRY(q2, 2, 4096)
        RETRY(q3, 3, 6144) RETRY(q4, 4, 8192) RETRY(q5, 5, 10240)
        RETRY(q6, 6, 12288) RETRY(q7, 7, 14336)
#undef RETRY
      }
#define STRIP(Q, I)                                                          \
      {                                                                      \
        unsigned lo = __builtin_amdgcn_perm(Q[1], Q[0], 0x07060302u);        \
        unsigned hi = __builtin_amdgcn_perm(Q[3], Q[2], 0x07060302u);        \
        unsigned int* d =                                                    \
            reinterpret_cast<unsigned int*>(&Ald[2 * I + srow][scol4]);      \
        d[0] = lo; d[1] = hi;                                                \
      }
      STRIP(q0, 0) STRIP(q1, 1) STRIP(q2, 2) STRIP(q3, 3)
      STRIP(q4, 4) STRIP(q5, 5) STRIP(q6, 6) STRIP(q7, 7)
#undef STRIP
    }

    // xin load for t+2 (issued here; consumed a full step later)
    const int ts = (t + 2 < SEQ) ? t + 2 : SEQ - 1;
    const unsigned xnv = xu[(size_t)ts * 65536 + xoff];

    __syncthreads();  // B1: h_t staged in LDS

    floatx4 acc0 = (floatx4){0.f, 0.f, 0.f, 0.f};
    floatx4 acc1 = (floatx4){0.f, 0.f, 0.f, 0.f};
    if (t > 0) {
      const int kb = kg * 256 + lk;
#pragma unroll
      for (int kt = 0; kt < 8; ++kt) {
        half8 a = *reinterpret_cast<const half8*>(&Ald[l15][kb + kt * 32]);
        acc0 = __builtin_amdgcn_mfma_f32_16x16x32_f16(a, wf0[kt], acc0, 0, 0, 0);
        acc1 = __builtin_amdgcn_mfma_f32_16x16x32_f16(a, wf1[kt], acc1, 0, 0, 0);
      }
    }
    // publish K-quarter partials (kg-slot rotated; readers sum all 4)
    {
      const int slot = (kg + (l >> 3)) & 3;
#pragma unroll
      for (int i = 0; i < 4; ++i) {
        part[g][0][i][l][slot] = acc0[i];
        part[g][1][i][l][slot] = acc1[i];
      }
    }
    __syncthreads();  // B2: partials visible; also protects Ald WAR

    // finalize 2 adjacent cols (n0, n0+1) of row er
    const floatx4 p0 =
        *reinterpret_cast<const floatx4*>(&part[pg][pnt][pi][plane][0]);
    const floatx4 p1 =
        *reinterpret_cast<const floatx4*>(&part[pg][pnt][pi][plane + 1][0]);
    const float s0 = (p0[0] + p0[1]) + (p0[2] + p0[3]);
    const float s1 = (p1[0] + p1[1]) + (p1[2] + p1[3]);
    const float xv0 =
        (float)__builtin_bit_cast(_Float16, (unsigned short)(xc & 0xFFFFu));
    const float xv1 =
        (float)__builtin_bit_cast(_Float16, (unsigned short)(xc >> 16));
    float pre0 = fminf(fmaxf(s0 + xv0 + bias0, -15.f), 15.f);
    float pre1 = fminf(fmaxf(s1 + xv1 + bias1, -15.f), 15.f);
    const float e0 = __expf(2.f * pre0), e1 = __expf(2.f * pre1);
    h0 += ((e0 - 1.f) / (e0 + 1.f) - h0) * it0;
    h1 += ((e1 - 1.f) / (e1 + 1.f) - h1) * it1;

    if (t < SEQ - 1) {
      const unsigned short hb0 = __builtin_bit_cast(unsigned short, (_Float16)h0);
      const unsigned short hb1 = __builtin_bit_cast(unsigned short, (_Float16)h1);
      const unsigned wo0 = ((unsigned)hb0 << 16) | (unsigned)(t + 1);
      const unsigned wo1 = ((unsigned)hb1 << 16) | (unsigned)(t + 1);
      const unsigned long long dw =
          (unsigned long long)wo0 | ((unsigned long long)wo1 << 32);
      unsigned long long* sp = reinterpret_cast<unsigned long long*>(
          hbuf + (size_t)((t + 1) & 1) * 131072 + m * 16384 + er * 1024 + n0);
      __hip_atomic_store(sp, dw, __ATOMIC_RELAXED, __HIP_MEMORY_SCOPE_AGENT);
    } else {
      *reinterpret_cast<float2*>(&hfinal[(size_t)gb * HIDDEN + n0]) =
          (float2){h0, h1};
    }
    xc = x1v;
    x1v = xnv;
  }
}

// ---------------------------------------------------------------------------
// K3: out[B][256] = hfinal @ W_out + b_out
// ---------------------------------------------------------------------------
__global__ __launch_bounds__(256) void out_gemm(
    const float* __restrict__ hfinal, const float* __restrict__ Wout,
    const float* __restrict__ bout, float* __restrict__ out) {
  int b0 = blockIdx.x * 2;
  int o = threadIdx.x;
  float a0 = 0.f, a1 = 0.f;
  for (int k = 0; k < HIDDEN; ++k) {
    float wv = Wout[(size_t)k * OUTPUT + o];
    a0 += hfinal[(size_t)b0 * HIDDEN + k] * wv;
    a1 += hfinal[(size_t)(b0 + 1) * HIDDEN + k] * wv;
  }
  out[(size_t)b0 * OUTPUT + o] = a0 + bout[o];
  out[(size_t)(b0 + 1) * OUTPUT + o] = a1 + bout[o];
}

// ---------------------------------------------------------------------------
extern "C" void kernel_launch(void* const* d_in, const int* in_sizes, int n_in,
                              void* d_out, int out_size, void* d_ws,
                              size_t ws_size, hipStream_t stream) {
  const float* x     = (const float*)d_in[0];
  const float* W_in  = (const float*)d_in[1];
  const float* b_in  = (const float*)d_in[2];
  const float* W_h   = (const float*)d_in[3];
  const float* b_h   = (const float*)d_in[4];
  const float* tau   = (const float*)d_in[5];
  const float* W_out = (const float*)d_in[6];
  const float* b_out = (const float*)d_in[7];
  float* out = (float*)d_out;

  char* ws = (char*)d_ws;
  _Float16* xin = (_Float16*)ws;  ws += (size_t)BATCH * SEQ * HIDDEN * 2;  // 134MB
  _Float16* WinP = (_Float16*)ws; ws += (size_t)INPUT * HIDDEN * 2;        // 1MB
  _Float16* WhT = (_Float16*)ws;  ws += (size_t)HIDDEN * HIDDEN * 2;       // 2MB
  unsigned int* hbuf = (unsigned int*)ws;
  ws += (size_t)2 * BATCH * HIDDEN * 4;                                    // 1MB
  float* hfin = (float*)ws;       ws += (size_t)BATCH * HIDDEN * 4;        // 512KB

  // zero tags (tag 0 never polled: t=0 skips poll/MFMA since h_0 = 0)
  hipMemsetAsync(hbuf, 0, (size_t)2 * BATCH * HIDDEN * 4, stream);

  transpose_f32_to_f16<<<dim3(HIDDEN / 32, HIDDEN / 32), 256, 0, stream>>>(
      W_h, WhT, HIDDEN, HIDDEN);
  pack_win<<<(INPUT * HIDDEN) / 256, 256, 0, stream>>>(W_in, WinP);

  xin_gemm<<<(BATCH * SEQ / 64) * (HIDDEN / 128), 256, 0, stream>>>(x, WinP,
                                                                    xin);

  liquid_scan<<<128, 512, 0, stream>>>(xin, WhT, b_in, b_h, tau, hbuf, hfin);

  out_gemm<<<BATCH / 2, OUTPUT, 0, stream>>>(hfin, W_out, b_out, out);
}

// Round 14
// 1245.399 us; speedup vs baseline: 1.5682x; 1.5682x over previous
//
#include <hip/hip_runtime.h>
#include <hip/hip_fp16.h>

typedef _Float16 half8 __attribute__((ext_vector_type(8)));
typedef float floatx4 __attribute__((ext_vector_type(4)));
typedef unsigned int uintx4 __attribute__((ext_vector_type(4)));

#define INPUT  512
#define HIDDEN 1024
#define OUTPUT 256
#define BATCH  128
#define SEQ    512

// ---------------------------------------------------------------------------
// K0: transpose + fp32->fp16:  W_h [K][N] f32 -> WhT [N][K] f16
// ---------------------------------------------------------------------------
__global__ __launch_bounds__(256) void transpose_f32_to_f16(
    const float* __restrict__ in, _Float16* __restrict__ out, int K, int N) {
  __shared__ float tile[32][33];
  int bi = blockIdx.x;
  int bj = blockIdx.y;
  int cc = threadIdx.x & 31;
  int rr = threadIdx.x >> 5;
#pragma unroll
  for (int s = 0; s < 4; ++s) {
    int r = rr + 8 * s;
    tile[r][cc] = in[(size_t)(bi * 32 + r) * N + bj * 32 + cc];
  }
  __syncthreads();
#pragma unroll
  for (int s = 0; s < 4; ++s) {
    int nl = rr + 8 * s;
    out[(size_t)(bj * 32 + nl) * K + bi * 32 + cc] = (_Float16)tile[cc][nl];
  }
}

// ---------------------------------------------------------------------------
// K0b: pack W_in [512][1024] f32 into MFMA B-fragment order (fp16).
// ---------------------------------------------------------------------------
__global__ __launch_bounds__(256) void pack_win(
    const float* __restrict__ W, _Float16* __restrict__ P) {
  int idx = blockIdx.x * 256 + threadIdx.x;   // 0..524287
  int k = idx >> 10, n = idx & 1023;
  P[((size_t)(k >> 5) << 15) + (n << 5) + (k & 31)] = (_Float16)W[idx];
}

// ---------------------------------------------------------------------------
// K1: xin[S][B][H] = x @ W_in  (time-major).  R14: 256x128 tile, 4 waves,
// each wave owns 64 rows (4x16 strips) and reuses every B fragment for 4
// MFMAs -> B L2-traffic 4.2GB -> 1.0GB (B bytes = 67GB / rows-per-wave).
// ---------------------------------------------------------------------------
__global__ __launch_bounds__(256, 1) void xin_gemm(
    const float* __restrict__ x, const _Float16* __restrict__ WinP,
    _Float16* __restrict__ xin) {
  int bid = blockIdx.x;                            // 2048 blocks
  int bm = (bid & 7) * 32 + ((bid >> 3) & 31);     // 0..255 (XCD-sliced)
  int bn = bid >> 8;                               // 0..7
  int tid = threadIdx.x;
  int l = tid & 63;
  int w = tid >> 6;                                // wave 0..3
  int l15 = l & 15;
  int lk = (l >> 4) << 3;

  const int rowbase = bm * 256 + w * 64;           // wave's 64 rows
  const int colbase = bn * 128;

  floatx4 acc[4][8];
#pragma unroll
  for (int s = 0; s < 4; ++s)
#pragma unroll
    for (int nt = 0; nt < 8; ++nt) acc[s][nt] = (floatx4){0.f, 0.f, 0.f, 0.f};

  const float* xr0 = x + (size_t)(rowbase + l15) * INPUT;

  for (int k0 = 0; k0 < INPUT; k0 += 32) {
    int ak = k0 + lk;
    half8 a[4];
#pragma unroll
    for (int s = 0; s < 4; ++s) {
      const float* xr = xr0 + (size_t)(s * 16) * INPUT;
      float4 xa = *reinterpret_cast<const float4*>(xr + ak);
      float4 xb = *reinterpret_cast<const float4*>(xr + ak + 4);
      a[s][0] = (_Float16)xa.x; a[s][1] = (_Float16)xa.y;
      a[s][2] = (_Float16)xa.z; a[s][3] = (_Float16)xa.w;
      a[s][4] = (_Float16)xb.x; a[s][5] = (_Float16)xb.y;
      a[s][6] = (_Float16)xb.z; a[s][7] = (_Float16)xb.w;
    }
    const _Float16* pq = WinP + ((size_t)(k0 >> 5) << 15) + l15 * 32 + lk;
#pragma unroll
    for (int nt = 0; nt < 8; ++nt) {
      half8 b = *reinterpret_cast<const half8*>(pq + (colbase + nt * 16) * 32);
#pragma unroll
      for (int s = 0; s < 4; ++s)
        acc[s][nt] = __builtin_amdgcn_mfma_f32_16x16x32_f16(a[s], b,
                                                            acc[s][nt], 0, 0, 0);
    }
  }

#pragma unroll
  for (int s = 0; s < 4; ++s) {
    int orow = rowbase + s * 16 + ((l >> 4) << 2);
#pragma unroll
    for (int nt = 0; nt < 8; ++nt)
#pragma unroll
      for (int i = 0; i < 4; ++i) {
        int r = orow + i;
        int b = r >> 9;
        int ss = r & 511;
        xin[((size_t)ss * BATCH + b) * HIDDEN + colbase + nt * 16 + l15] =
            (_Float16)acc[s][nt][i];
      }
  }
}

// ---------------------------------------------------------------------------
// K2: persistent recurrence — R10 VERBATIM (proven 977us; 5 attempted
// restructures all regressed — this is the frozen local optimum).
// 128 blocks = 8 batch-groups (16 rows, -> XCD m) x 16 N-slices (64 cols).
// 8 waves = 2 ntile-pairs (g) x 4 K-quarters (kg); W_h stationary in VGPRs.
// Tagged-word exchange; cooperative contiguous poll -> LDS stage -> frags.
// ---------------------------------------------------------------------------
__global__ __launch_bounds__(512) void liquid_scan(
    const _Float16* __restrict__ xin,   // [S][B][H]
    const _Float16* __restrict__ WhT,   // [H n][H k]
    const float* __restrict__ b_in, const float* __restrict__ b_h,
    const float* __restrict__ tau,
    unsigned int* hbuf,                 // [2][8][16][1024] tagged u32
    float* __restrict__ hfinal) {       // [B][H] f32
  int blk = blockIdx.x;
  int m = blk & 7;                  // batch group -> XCD m (perf heuristic)
  int j = blk >> 3;                 // N slice, 0..15
  int tid = threadIdx.x;
  int l = tid & 63;
  int w = tid >> 6;                 // 0..7
  int g = w & 1;                    // ntile-pair (32 cols)
  int kg = w >> 1;                  // K quarter (256 k)
  int l15 = l & 15;
  int lk = (l >> 4) << 3;

  __shared__ _Float16 Ald[16][1032];         // h_t tile (R7 proven layout)
  __shared__ float part[2][2][4][64][4];     // [g][nt2][i][lane][kg-slot]

  // ---- stationary W_h: two ntiles x K-quarter per wave (64 VGPR) ----
  half8 wf0[8], wf1[8];
  {
    const _Float16* wb0 =
        WhT + (size_t)(j * 64 + g * 32 + l15) * HIDDEN + kg * 256 + lk;
    const _Float16* wb1 = wb0 + 16 * HIDDEN;
#pragma unroll
    for (int kt = 0; kt < 8; ++kt) {
      wf0[kt] = *reinterpret_cast<const half8*>(wb0 + kt * 32);
      wf1[kt] = *reinterpret_cast<const half8*>(wb1 + kt * 32);
    }
  }

  // ---- finalize mapping: thread -> rows {2w',2w'+1}, col l' ----
  const int wp = tid >> 6;
  const int lp = tid & 63;
  const int gc = j * 64 + lp;
  const float bias_c = b_in[gc] + b_h[gc];
  const float invtau_c = 1.0f / tau[gc];
  float hown[2] = {0.f, 0.f};
  const int r0 = 2 * wp;
  const int gb0 = m * 16 + r0;
  const int ntg = lp >> 5;
  const int nt2 = (lp >> 4) & 1;
  const int lsrc0 = (((r0 + 0) >> 2) << 4) | (lp & 15);
  const int lsrc1 = (((r0 + 1) >> 2) << 4) | (lp & 15);
  const int i_0 = (r0 + 0) & 3;
  const int i_1 = (r0 + 1) & 3;

  // ---- poll assignment (R7 verbatim): thread's 8 slabs ----
  const int srow = tid >> 8;
  const int scol4 = (tid & 255) * 4;
  unsigned int* gbase = hbuf + m * 16384 + tid * 4;

  // ---- xin 2-deep pipeline: rows gb0, gb0+1 at col gc ----
  _Float16 xc[2], x1[2], xn[2];
#pragma unroll
  for (int b = 0; b < 2; ++b) {
    xc[b] = xin[((size_t)0 * BATCH + gb0 + b) * HIDDEN + gc];
    x1[b] = xin[((size_t)1 * BATCH + gb0 + b) * HIDDEN + gc];
  }

  for (int t = 0; t < SEQ; ++t) {
    if (t > 0) {
      unsigned int* bp = gbase + (size_t)(t & 1) * 131072;
      const unsigned want = (unsigned)t;
      uintx4 q0, q1, q2, q3, q4, q5, q6, q7;
      for (;;) {
        // fused issue+wait: no load outlives its asm statement (R5 lesson)
        asm volatile(
            "global_load_dwordx4 %0, %8, off sc1\n\t"
            "global_load_dwordx4 %1, %9, off sc1\n\t"
            "global_load_dwordx4 %2, %10, off sc1\n\t"
            "global_load_dwordx4 %3, %11, off sc1\n\t"
            "global_load_dwordx4 %4, %12, off sc1\n\t"
            "global_load_dwordx4 %5, %13, off sc1\n\t"
            "global_load_dwordx4 %6, %14, off sc1\n\t"
            "global_load_dwordx4 %7, %15, off sc1\n\t"
            "s_waitcnt vmcnt(0)"
            : "=&v"(q0), "=&v"(q1), "=&v"(q2), "=&v"(q3),
              "=&v"(q4), "=&v"(q5), "=&v"(q6), "=&v"(q7)
            : "v"(bp), "v"(bp + 2048), "v"(bp + 4096), "v"(bp + 6144),
              "v"(bp + 8192), "v"(bp + 10240), "v"(bp + 12288),
              "v"(bp + 14336)
            : "memory");
        unsigned bad = 0;
#define CH(Q) bad |= ((Q[0] ^ want) | (Q[1] ^ want) | (Q[2] ^ want) | \
                      (Q[3] ^ want)) & 0xFFFFu;
        CH(q0) CH(q1) CH(q2) CH(q3) CH(q4) CH(q5) CH(q6) CH(q7)
#undef CH
        if (!__any((int)(bad != 0u))) break;
      }
#define STRIP(Q, I)                                                          \
      {                                                                      \
        unsigned lo = __builtin_amdgcn_perm(Q[1], Q[0], 0x07060302u);        \
        unsigned hi = __builtin_amdgcn_perm(Q[3], Q[2], 0x07060302u);        \
        unsigned int* d =                                                    \
            reinterpret_cast<unsigned int*>(&Ald[2 * I + srow][scol4]);      \
        d[0] = lo; d[1] = hi;                                                \
      }
      STRIP(q0, 0) STRIP(q1, 1) STRIP(q2, 2) STRIP(q3, 3)
      STRIP(q4, 4) STRIP(q5, 5) STRIP(q6, 6) STRIP(q7, 7)
#undef STRIP
    }

    // xin loads for t+2 (issued here; consumed a full step later)
    {
      const int ts = (t + 2 < SEQ) ? t + 2 : SEQ - 1;
      xn[0] = xin[((size_t)ts * BATCH + gb0) * HIDDEN + gc];
      xn[1] = xin[((size_t)ts * BATCH + gb0 + 1) * HIDDEN + gc];
    }
    __syncthreads();  // B1: h_t staged in LDS

    floatx4 acc0 = (floatx4){0.f, 0.f, 0.f, 0.f};
    floatx4 acc1 = (floatx4){0.f, 0.f, 0.f, 0.f};
    if (t > 0) {
      const int kb = kg * 256 + lk;
#pragma unroll
      for (int kt = 0; kt < 8; ++kt) {
        half8 a = *reinterpret_cast<const half8*>(&Ald[l15][kb + kt * 32]);
        acc0 = __builtin_amdgcn_mfma_f32_16x16x32_f16(a, wf0[kt], acc0, 0, 0, 0);
        acc1 = __builtin_amdgcn_mfma_f32_16x16x32_f16(a, wf1[kt], acc1, 0, 0, 0);
      }
    }
    // publish K-quarter partials (kg-slot rotated; readers sum all 4)
    {
      const int slot = (kg + (l >> 3)) & 3;
#pragma unroll
      for (int i = 0; i < 4; ++i) {
        part[g][0][i][l][slot] = acc0[i];
        part[g][1][i][l][slot] = acc1[i];
      }
    }
    __syncthreads();  // B2: partials visible; also protects Ald WAR

    unsigned int* outb = hbuf + (size_t)((t + 1) & 1) * 131072 + m * 16384;
#pragma unroll
    for (int b = 0; b < 2; ++b) {
      const floatx4 p = *reinterpret_cast<const floatx4*>(
          &part[ntg][nt2][b ? i_1 : i_0][b ? lsrc1 : lsrc0][0]);
      const float s = (p[0] + p[1]) + (p[2] + p[3]);
      float pre = s + (float)xc[b] + bias_c;
      pre = fminf(fmaxf(pre, -15.f), 15.f);
      const float e = __expf(2.f * pre);
      const float dx = (e - 1.f) / (e + 1.f);
      const float hn = hown[b] + (dx - hown[b]) * invtau_c;
      hown[b] = hn;
      if (t < SEQ - 1) {
        const unsigned short hb =
            __builtin_bit_cast(unsigned short, (_Float16)hn);
        const unsigned word = ((unsigned)hb << 16) | (unsigned)(t + 1);
        __hip_atomic_store(outb + (r0 + b) * 1024 + gc, word,
                           __ATOMIC_RELAXED, __HIP_MEMORY_SCOPE_AGENT);
      } else {
        hfinal[(size_t)(gb0 + b) * HIDDEN + gc] = hn;
      }
    }
    // rotate xin pipeline
    xc[0] = x1[0]; xc[1] = x1[1];
    x1[0] = xn[0]; x1[1] = xn[1];
  }
}

// ---------------------------------------------------------------------------
// K3: out[B][256] = hfinal @ W_out + b_out
// ---------------------------------------------------------------------------
__global__ __launch_bounds__(256) void out_gemm(
    const float* __restrict__ hfinal, const float* __restrict__ Wout,
    const float* __restrict__ bout, float* __restrict__ out) {
  int b0 = blockIdx.x * 2;
  int o = threadIdx.x;
  float a0 = 0.f, a1 = 0.f;
  for (int k = 0; k < HIDDEN; ++k) {
    float wv = Wout[(size_t)k * OUTPUT + o];
    a0 += hfinal[(size_t)b0 * HIDDEN + k] * wv;
    a1 += hfinal[(size_t)(b0 + 1) * HIDDEN + k] * wv;
  }
  out[(size_t)b0 * OUTPUT + o] = a0 + bout[o];
  out[(size_t)(b0 + 1) * OUTPUT + o] = a1 + bout[o];
}

// ---------------------------------------------------------------------------
extern "C" void kernel_launch(void* const* d_in, const int* in_sizes, int n_in,
                              void* d_out, int out_size, void* d_ws,
                              size_t ws_size, hipStream_t stream) {
  const float* x     = (const float*)d_in[0];
  const float* W_in  = (const float*)d_in[1];
  const float* b_in  = (const float*)d_in[2];
  const float* W_h   = (const float*)d_in[3];
  const float* b_h   = (const float*)d_in[4];
  const float* tau   = (const float*)d_in[5];
  const float* W_out = (const float*)d_in[6];
  const float* b_out = (const float*)d_in[7];
  float* out = (float*)d_out;

  char* ws = (char*)d_ws;
  _Float16* xin = (_Float16*)ws;  ws += (size_t)BATCH * SEQ * HIDDEN * 2;  // 134MB
  _Float16* WinP = (_Float16*)ws; ws += (size_t)INPUT * HIDDEN * 2;        // 1MB
  _Float16* WhT = (_Float16*)ws;  ws += (size_t)HIDDEN * HIDDEN * 2;       // 2MB
  unsigned int* hbuf = (unsigned int*)ws;
  ws += (size_t)2 * BATCH * HIDDEN * 4;                                    // 1MB
  float* hfin = (float*)ws;       ws += (size_t)BATCH * HIDDEN * 4;        // 512KB

  // zero tags (tag 0 never polled: t=0 skips poll/MFMA since h_0 = 0)
  hipMemsetAsync(hbuf, 0, (size_t)2 * BATCH * HIDDEN * 4, stream);

  transpose_f32_to_f16<<<dim3(HIDDEN / 32, HIDDEN / 32), 256, 0, stream>>>(
      W_h, WhT, HIDDEN, HIDDEN);
  pack_win<<<(INPUT * HIDDEN) / 256, 256, 0, stream>>>(W_in, WinP);

  xin_gemm<<<(BATCH * SEQ / 256) * (HIDDEN / 128), 256, 0, stream>>>(x, WinP,
                                                                     xin);

  liquid_scan<<<128, 512, 0, stream>>>(xin, WhT, b_in, b_h, tau, hbuf, hfin);

  out_gemm<<<BATCH / 2, OUTPUT, 0, stream>>>(hfin, W_out, b_out, out);
}